// Round 1
// baseline (1550.078 us; speedup 1.0000x reference)
//
#include <hip/hip_runtime.h>
#include <hip/hip_bf16.h>

#define BB 2
#define LL 2048
#define DM 512
#define HH 8
#define DH 64
#define BH (BB*HH)            // 16
#define SCALE 0.02209708691207961f   // 1/sqrt(2048)

// ws layout (floats):
//  Qp: [BH][L][64]   offset 0        (2,097,152)
//  Kp: [BH][L][64]   offset 2097152
//  Vp: [BH][L][64]   offset 4194304
//  Sinv: [BH][L]     offset 6291456  (32768)   -- 1/sum_q exp(y[q,k])
#define OFF_Q  0
#define OFF_K  2097152
#define OFF_V  4194304
#define OFF_S  6291456

// ---------------- Projection: out[bh,l,e] = sum_d in[b,l,d] * W[h,d,e] ----------------
__global__ __launch_bounds__(256) void proj_kernel(
    const float* __restrict__ keys, const float* __restrict__ queries,
    const float* __restrict__ values, const float* __restrict__ WQ,
    const float* __restrict__ WK, const float* __restrict__ WV,
    float* __restrict__ ws) {
  int t = threadIdx.x;
  int e = t & 63;
  int lsub = t >> 6;
  int row = blockIdx.x * 4 + lsub;        // 0..BH*L-1
  int bh = row >> 11;
  int l = row & 2047;
  int b = bh >> 3;
  int h = bh & 7;
  int z = blockIdx.y;
  const float* in; const float* W; float* out;
  if (z == 0)      { in = queries; W = WQ; out = ws + OFF_Q; }
  else if (z == 1) { in = keys;    W = WK; out = ws + OFF_K; }
  else             { in = values;  W = WV; out = ws + OFF_V; }
  const float* inrow = in + ((size_t)b * LL + l) * DM;
  const float* Wh = W + (size_t)h * DM * DH + e;
  float acc = 0.f;
#pragma unroll 4
  for (int d = 0; d < DM; d += 4) {
    float4 v = *(const float4*)(inrow + d);
    acc += v.x * Wh[(d + 0) * 64];
    acc += v.y * Wh[(d + 1) * 64];
    acc += v.z * Wh[(d + 2) * 64];
    acc += v.w * Wh[(d + 3) * 64];
  }
  out[((size_t)bh * LL + l) * 64 + e] = acc;
}

// ---------------- Column stats: Sinv[bh,k] = 1 / sum_q exp(SCALE * Q[q,:]·K[k,:]) ----------------
__global__ __launch_bounds__(256) void stats_kernel(float* __restrict__ ws) {
  const float* Qp = ws + OFF_Q;
  const float* Kp = ws + OFF_K;
  float* Sinv = ws + OFF_S;
  int t = threadIdx.x;
  int klane = t & 63;
  int qg = t >> 6;                 // 0..3
  int bh = blockIdx.y;
  int kbase = blockIdx.x * 64;

  __shared__ float Ks[64][68];
  __shared__ float Qs[64][64];
  __shared__ float red[4][64];

  // stage K tile (coalesced)
  const float* Kg = Kp + ((size_t)bh * LL + kbase) * 64;
#pragma unroll
  for (int r = 0; r < 4; ++r) {
    int f = t + 256 * r;           // float4 index 0..1023
    int kk = f >> 4, dc = f & 15;
    *(float4*)&Ks[kk][dc * 4] = *(const float4*)(Kg + kk * 64 + dc * 4);
  }
  __syncthreads();

  // register-cache this thread's K row
  float kr[64];
#pragma unroll
  for (int i = 0; i < 16; ++i) {
    float4 v = *(const float4*)&Ks[klane][4 * i];
    kr[4 * i] = v.x; kr[4 * i + 1] = v.y; kr[4 * i + 2] = v.z; kr[4 * i + 3] = v.w;
  }

  float ssum = 0.f;
  const float* Qg = Qp + (size_t)bh * LL * 64;
  for (int qt = 0; qt < 32; ++qt) {
    __syncthreads();
#pragma unroll
    for (int r = 0; r < 4; ++r) {
      int f = t + 256 * r;
      int qq = f >> 4, dc = f & 15;
      *(float4*)&Qs[qq][dc * 4] = *(const float4*)(Qg + (size_t)(qt * 64 + qq) * 64 + dc * 4);
    }
    __syncthreads();
    for (int qi = 0; qi < 16; ++qi) {
      int q = qg * 16 + qi;
      float acc = 0.f;
#pragma unroll
      for (int i = 0; i < 16; ++i) {
        float4 qv = *(const float4*)&Qs[q][4 * i];
        acc += qv.x * kr[4 * i] + qv.y * kr[4 * i + 1] + qv.z * kr[4 * i + 2] + qv.w * kr[4 * i + 3];
      }
      ssum += __expf(acc * SCALE);   // |acc*SCALE| <~ 1.3, no max needed
    }
  }
  red[qg][klane] = ssum;
  __syncthreads();
  if (t < 64) {
    float s = red[0][t] + red[1][t] + red[2][t] + red[3][t];
    Sinv[(size_t)bh * LL + kbase + t] = 1.0f / s;
  }
}

// ---------------- Attention: out[q,e] = sum_k exp(SCALE*Q·K) * Sinv[k] * V[k,e] ----------------
__global__ __launch_bounds__(256) void attn_kernel(const float* __restrict__ ws,
                                                   float* __restrict__ out) {
  const float* Qp = ws + OFF_Q;
  const float* Kp = ws + OFF_K;
  const float* Vp = ws + OFF_V;
  const float* Sinv = ws + OFF_S;
  int t = threadIdx.x;
  int lane = t & 63;               // phase1: k-lane; phase2: e
  int qg = t >> 6;                 // 0..3
  int bh = blockIdx.y;
  int b = bh >> 3, h = bh & 7;
  int qbase = blockIdx.x * 64;

  __shared__ float Qs[64][64];
  __shared__ float Ks[64][68];
  __shared__ float Pt[64][64];
  __shared__ float Vs[64][64];

  // stage Q tile once (covered by first loop-top barrier)
  const float* Qg = Qp + ((size_t)bh * LL + qbase) * 64;
#pragma unroll
  for (int r = 0; r < 4; ++r) {
    int f = t + 256 * r;
    int qq = f >> 4, dc = f & 15;
    *(float4*)&Qs[qq][dc * 4] = *(const float4*)(Qg + qq * 64 + dc * 4);
  }

  float acc[16];
#pragma unroll
  for (int i = 0; i < 16; ++i) acc[i] = 0.f;

  for (int kt = 0; kt < 32; ++kt) {
    __syncthreads();   // prev iter done with Ks/Vs/Pt (and Q staging on iter 0)
    const float* Kg = Kp + ((size_t)bh * LL + kt * 64) * 64;
    const float* Vg = Vp + ((size_t)bh * LL + kt * 64) * 64;
    const float* Sg = Sinv + (size_t)bh * LL + kt * 64;
#pragma unroll
    for (int r = 0; r < 4; ++r) {
      int f = t + 256 * r;
      int kk = f >> 4, dc = f & 15;
      *(float4*)&Ks[kk][dc * 4] = *(const float4*)(Kg + kk * 64 + dc * 4);
      float4 v = *(const float4*)(Vg + kk * 64 + dc * 4);
      float sc = Sg[kk];
      v.x *= sc; v.y *= sc; v.z *= sc; v.w *= sc;
      *(float4*)&Vs[kk][dc * 4] = v;
    }
    __syncthreads();

    // phase 1: P[q][k] = exp(SCALE * Q[q,:]·K[k,:])
    {
      float kr[64];
#pragma unroll
      for (int i = 0; i < 16; ++i) {
        float4 v = *(const float4*)&Ks[lane][4 * i];
        kr[4 * i] = v.x; kr[4 * i + 1] = v.y; kr[4 * i + 2] = v.z; kr[4 * i + 3] = v.w;
      }
      for (int qi = 0; qi < 16; ++qi) {
        int q = qg * 16 + qi;
        float d0 = 0.f;
#pragma unroll
        for (int i = 0; i < 16; ++i) {
          float4 qv = *(const float4*)&Qs[q][4 * i];
          d0 += qv.x * kr[4 * i] + qv.y * kr[4 * i + 1] + qv.z * kr[4 * i + 2] + qv.w * kr[4 * i + 3];
        }
        Pt[q][lane] = __expf(d0 * SCALE);
      }
    }
    __syncthreads();

    // phase 2: acc[qi] += P[q][k] * Vs[k][e]
#pragma unroll 4
    for (int kc = 0; kc < 16; ++kc) {
      float v0 = Vs[kc * 4 + 0][lane];
      float v1 = Vs[kc * 4 + 1][lane];
      float v2 = Vs[kc * 4 + 2][lane];
      float v3 = Vs[kc * 4 + 3][lane];
#pragma unroll
      for (int qi = 0; qi < 16; ++qi) {
        float4 p = *(const float4*)&Pt[qg * 16 + qi][kc * 4];
        acc[qi] += p.x * v0 + p.y * v1 + p.z * v2 + p.w * v3;
      }
    }
  }

  // out[b, q, h*64 + e]
  float* og = out + ((size_t)b * LL + qbase) * (HH * DH) + h * DH + lane;
#pragma unroll
  for (int qi = 0; qi < 16; ++qi) {
    og[(size_t)(qg * 16 + qi) * (HH * DH)] = acc[qi];
  }
}

extern "C" void kernel_launch(void* const* d_in, const int* in_sizes, int n_in,
                              void* d_out, int out_size, void* d_ws, size_t ws_size,
                              hipStream_t stream) {
  const float* keys    = (const float*)d_in[0];
  const float* queries = (const float*)d_in[1];
  const float* values  = (const float*)d_in[2];
  const float* WQ      = (const float*)d_in[3];
  const float* WK      = (const float*)d_in[4];
  const float* WV      = (const float*)d_in[5];
  float* out = (float*)d_out;
  float* ws  = (float*)d_ws;

  proj_kernel<<<dim3(BH * LL / 4, 3), 256, 0, stream>>>(keys, queries, values, WQ, WK, WV, ws);
  stats_kernel<<<dim3(LL / 64, BH), 256, 0, stream>>>(ws);
  attn_kernel<<<dim3(LL / 64, BH), 256, 0, stream>>>(ws, out);
}

// Round 2
// 909.281 us; speedup vs baseline: 1.7047x; 1.7047x over previous
//
#include <hip/hip_runtime.h>
#include <hip/hip_bf16.h>

#define BB 2
#define LL 2048
#define DM 512
#define HH 8
#define DH 64
#define BH (BB*HH)            // 16
#define SCALE 0.02209708691207961f   // 1/sqrt(2048)

// ws layout (floats):
//  Qp: [BH][L][64]   offset 0        (2,097,152)
//  Kp: [BH][L][64]   offset 2097152
//  Vp: [BH][L][64]   offset 4194304
//  Sinv: [BH][L]     offset 6291456  (32768)   -- 1/sum_q exp(y[q,k])
#define OFF_Q  0
#define OFF_K  2097152
#define OFF_V  4194304
#define OFF_S  6291456

typedef __attribute__((ext_vector_type(8))) short short8;    // 8 bf16 (4 VGPRs)
typedef __attribute__((ext_vector_type(4))) float f32x4;     // MFMA C/D

__device__ __forceinline__ short f2bf(float f) {
  union { float f; unsigned u; } v; v.f = f;
  unsigned r = v.u + 0x7fff + ((v.u >> 16) & 1);   // RNE
  return (short)(r >> 16);
}

// ---------------- Projection via MFMA: out[bh,l,e] = sum_d in[b,l,d] * W[h,d,e] ----------------
// Block: 64 rows x 64 e, K-tiles of 32. A,B staged to LDS as bf16 (B transposed so
// both fragments read 16B/lane contiguous). Output written fp32 (same layout as before).
__global__ __launch_bounds__(256) void proj_mfma_kernel(
    const float* __restrict__ keys, const float* __restrict__ queries,
    const float* __restrict__ values, const float* __restrict__ WQ,
    const float* __restrict__ WK, const float* __restrict__ WV,
    float* __restrict__ ws) {
  int t = threadIdx.x;
  int z = blockIdx.z;
  int bh = blockIdx.y;
  int b = bh >> 3, h = bh & 7;
  int qbase = blockIdx.x * 64;
  const float* in; const float* W; float* out;
  if (z == 0)      { in = queries; W = WQ; out = ws + OFF_Q; }
  else if (z == 1) { in = keys;    W = WK; out = ws + OFF_K; }
  else             { in = values;  W = WV; out = ws + OFF_V; }
  const float* inbase = in + ((size_t)b * LL + qbase) * DM;
  const float* Wh = W + (size_t)h * DM * DH;

  // stride 40 bf16 = 80 B: 16B-aligned rows for b128 frag reads, breaks pow2 banks
  __shared__ __align__(16) short As[64 * 40];
  __shared__ __align__(16) short Bs[64 * 40];

  int lane = t & 63, w = t >> 6;
  int quad = lane >> 4, l16 = lane & 15;

  f32x4 acc[4];
#pragma unroll
  for (int et = 0; et < 4; ++et) acc[et] = (f32x4){0.f, 0.f, 0.f, 0.f};

  for (int kt = 0; kt < 16; ++kt) {
    __syncthreads();   // previous iter's frag reads done
    // stage A: 64 rows x 32 k, f32 -> bf16
#pragma unroll
    for (int rep = 0; rep < 2; ++rep) {
      int f4 = t + rep * 256;        // 0..511 float4s
      int row = f4 >> 3, c4 = f4 & 7;
      float4 v = *(const float4*)(inbase + (size_t)row * DM + kt * 32 + c4 * 4);
      short* dst = &As[row * 40 + c4 * 4];
      dst[0] = f2bf(v.x); dst[1] = f2bf(v.y); dst[2] = f2bf(v.z); dst[3] = f2bf(v.w);
    }
    // stage B transposed: Bs[e][k] = W[kt*32+k][e]
#pragma unroll
    for (int rep = 0; rep < 2; ++rep) {
      int f4 = t + rep * 256;        // 0..511 float4s
      int d = f4 >> 4, e4 = f4 & 15;
      float4 v = *(const float4*)(Wh + (size_t)(kt * 32 + d) * 64 + e4 * 4);
      Bs[(e4 * 4 + 0) * 40 + d] = f2bf(v.x);
      Bs[(e4 * 4 + 1) * 40 + d] = f2bf(v.y);
      Bs[(e4 * 4 + 2) * 40 + d] = f2bf(v.z);
      Bs[(e4 * 4 + 3) * 40 + d] = f2bf(v.w);
    }
    __syncthreads();
    // A-frag: lane holds A[m=l16][k=quad*8+j]; B-frag: B[k=quad*8+j][n=l16] = Bs[n][k]
    short8 a = *(const short8*)&As[(w * 16 + l16) * 40 + quad * 8];
#pragma unroll
    for (int et = 0; et < 4; ++et) {
      short8 bf = *(const short8*)&Bs[(et * 16 + l16) * 40 + quad * 8];
      acc[et] = __builtin_amdgcn_mfma_f32_16x16x32_bf16(a, bf, acc[et], 0, 0, 0);
    }
  }
  // C/D layout: col = l16, row = quad*4 + r (within wave's 16-row tile)
  float* og = out + ((size_t)bh * LL + qbase) * 64;
#pragma unroll
  for (int et = 0; et < 4; ++et)
#pragma unroll
    for (int r = 0; r < 4; ++r)
      og[(size_t)(w * 16 + quad * 4 + r) * 64 + et * 16 + l16] = acc[et][r];
}

// ---------------- Column stats: Sinv[bh,k] = 1 / sum_q exp(SCALE * Q[q,:]·K[k,:]) ----------------
__global__ __launch_bounds__(256) void stats_kernel(float* __restrict__ ws) {
  const float* Qp = ws + OFF_Q;
  const float* Kp = ws + OFF_K;
  float* Sinv = ws + OFF_S;
  int t = threadIdx.x;
  int klane = t & 63;
  int qg = t >> 6;                 // 0..3
  int bh = blockIdx.y;
  int kbase = blockIdx.x * 64;

  __shared__ float Ks[64][68];
  __shared__ float Qs[64][64];
  __shared__ float red[4][64];

  const float* Kg = Kp + ((size_t)bh * LL + kbase) * 64;
#pragma unroll
  for (int r = 0; r < 4; ++r) {
    int f = t + 256 * r;
    int kk = f >> 4, dc = f & 15;
    *(float4*)&Ks[kk][dc * 4] = *(const float4*)(Kg + kk * 64 + dc * 4);
  }
  __syncthreads();

  float kr[64];
#pragma unroll
  for (int i = 0; i < 16; ++i) {
    float4 v = *(const float4*)&Ks[klane][4 * i];
    kr[4 * i] = v.x; kr[4 * i + 1] = v.y; kr[4 * i + 2] = v.z; kr[4 * i + 3] = v.w;
  }

  float ssum = 0.f;
  const float* Qg = Qp + (size_t)bh * LL * 64;
  for (int qt = 0; qt < 32; ++qt) {
    __syncthreads();
#pragma unroll
    for (int r = 0; r < 4; ++r) {
      int f = t + 256 * r;
      int qq = f >> 4, dc = f & 15;
      *(float4*)&Qs[qq][dc * 4] = *(const float4*)(Qg + (size_t)(qt * 64 + qq) * 64 + dc * 4);
    }
    __syncthreads();
    for (int qi = 0; qi < 16; ++qi) {
      int q = qg * 16 + qi;
      float acc = 0.f;
#pragma unroll
      for (int i = 0; i < 16; ++i) {
        float4 qv = *(const float4*)&Qs[q][4 * i];
        acc += qv.x * kr[4 * i] + qv.y * kr[4 * i + 1] + qv.z * kr[4 * i + 2] + qv.w * kr[4 * i + 3];
      }
      ssum += __expf(acc * SCALE);
    }
  }
  red[qg][klane] = ssum;
  __syncthreads();
  if (t < 64) {
    float s = red[0][t] + red[1][t] + red[2][t] + red[3][t];
    Sinv[(size_t)bh * LL + kbase + t] = 1.0f / s;
  }
}

// ---------------- Attention: out[q,e] = sum_k exp(SCALE*Q·K) * Sinv[k] * V[k,e] ----------------
__global__ __launch_bounds__(256) void attn_kernel(const float* __restrict__ ws,
                                                   float* __restrict__ out) {
  const float* Qp = ws + OFF_Q;
  const float* Kp = ws + OFF_K;
  const float* Vp = ws + OFF_V;
  const float* Sinv = ws + OFF_S;
  int t = threadIdx.x;
  int lane = t & 63;
  int qg = t >> 6;
  int bh = blockIdx.y;
  int b = bh >> 3, h = bh & 7;
  int qbase = blockIdx.x * 64;

  __shared__ float Qs[64][64];
  __shared__ float Ks[64][68];
  __shared__ float Pt[64][64];
  __shared__ float Vs[64][64];

  const float* Qg = Qp + ((size_t)bh * LL + qbase) * 64;
#pragma unroll
  for (int r = 0; r < 4; ++r) {
    int f = t + 256 * r;
    int qq = f >> 4, dc = f & 15;
    *(float4*)&Qs[qq][dc * 4] = *(const float4*)(Qg + qq * 64 + dc * 4);
  }

  float acc[16];
#pragma unroll
  for (int i = 0; i < 16; ++i) acc[i] = 0.f;

  for (int kt = 0; kt < 32; ++kt) {
    __syncthreads();
    const float* Kg = Kp + ((size_t)bh * LL + kt * 64) * 64;
    const float* Vg = Vp + ((size_t)bh * LL + kt * 64) * 64;
    const float* Sg = Sinv + (size_t)bh * LL + kt * 64;
#pragma unroll
    for (int r = 0; r < 4; ++r) {
      int f = t + 256 * r;
      int kk = f >> 4, dc = f & 15;
      *(float4*)&Ks[kk][dc * 4] = *(const float4*)(Kg + kk * 64 + dc * 4);
      float4 v = *(const float4*)(Vg + kk * 64 + dc * 4);
      float sc = Sg[kk];
      v.x *= sc; v.y *= sc; v.z *= sc; v.w *= sc;
      *(float4*)&Vs[kk][dc * 4] = v;
    }
    __syncthreads();

    {
      float kr[64];
#pragma unroll
      for (int i = 0; i < 16; ++i) {
        float4 v = *(const float4*)&Ks[lane][4 * i];
        kr[4 * i] = v.x; kr[4 * i + 1] = v.y; kr[4 * i + 2] = v.z; kr[4 * i + 3] = v.w;
      }
      for (int qi = 0; qi < 16; ++qi) {
        int q = qg * 16 + qi;
        float d0 = 0.f;
#pragma unroll
        for (int i = 0; i < 16; ++i) {
          float4 qv = *(const float4*)&Qs[q][4 * i];
          d0 += qv.x * kr[4 * i] + qv.y * kr[4 * i + 1] + qv.z * kr[4 * i + 2] + qv.w * kr[4 * i + 3];
        }
        Pt[q][lane] = __expf(d0 * SCALE);
      }
    }
    __syncthreads();

#pragma unroll 4
    for (int kc = 0; kc < 16; ++kc) {
      float v0 = Vs[kc * 4 + 0][lane];
      float v1 = Vs[kc * 4 + 1][lane];
      float v2 = Vs[kc * 4 + 2][lane];
      float v3 = Vs[kc * 4 + 3][lane];
#pragma unroll
      for (int qi = 0; qi < 16; ++qi) {
        float4 p = *(const float4*)&Pt[qg * 16 + qi][kc * 4];
        acc[qi] += p.x * v0 + p.y * v1 + p.z * v2 + p.w * v3;
      }
    }
  }

  float* og = out + ((size_t)b * LL + qbase) * (HH * DH) + h * DH + lane;
#pragma unroll
  for (int qi = 0; qi < 16; ++qi) {
    og[(size_t)(qg * 16 + qi) * (HH * DH)] = acc[qi];
  }
}

extern "C" void kernel_launch(void* const* d_in, const int* in_sizes, int n_in,
                              void* d_out, int out_size, void* d_ws, size_t ws_size,
                              hipStream_t stream) {
  const float* keys    = (const float*)d_in[0];
  const float* queries = (const float*)d_in[1];
  const float* values  = (const float*)d_in[2];
  const float* WQ      = (const float*)d_in[3];
  const float* WK      = (const float*)d_in[4];
  const float* WV      = (const float*)d_in[5];
  float* out = (float*)d_out;
  float* ws  = (float*)d_ws;

  proj_mfma_kernel<<<dim3(LL / 64, BH, 3), 256, 0, stream>>>(keys, queries, values, WQ, WK, WV, ws);
  stats_kernel<<<dim3(LL / 64, BH), 256, 0, stream>>>(ws);
  attn_kernel<<<dim3(LL / 64, BH), 256, 0, stream>>>(ws, out);
}

// Round 3
// 189.071 us; speedup vs baseline: 8.1984x; 4.8092x over previous
//
#include <hip/hip_runtime.h>
#include <hip/hip_bf16.h>

#define BB 2
#define LL 2048
#define DM 512
#define HH 8
#define DH 64
#define BH 16
#define SCALE 0.02209708691207961f   // 1/sqrt(2048)

typedef unsigned short ushort_t;
typedef __attribute__((ext_vector_type(8))) short short8;    // 8 bf16 (4 VGPRs)
typedef __attribute__((ext_vector_type(4))) float f32x4;     // MFMA C/D

// ws layout (ushort element offsets):
//  Qb: [BH][L][64] bf16   @ 0
//  Kb: [BH][L][64] bf16   @ 2097152
//  Vt: [BH][64][L] bf16   @ 4194304   (V transposed: e-major)
//  Sinv: [BH][L] f32      @ 6291456 (as ushort offset; cast to float*)
#define OFFB_Q 0u
#define OFFB_K 2097152u
#define OFFB_V 4194304u
#define OFFB_S 6291456u

__device__ __forceinline__ ushort_t f2bf(float f) {
  union { float f; unsigned u; } v; v.f = f;
  unsigned r = v.u + 0x7fff + ((v.u >> 16) & 1);   // RNE
  return (ushort_t)(r >> 16);
}

// ---------------- Projection via MFMA -> bf16 outputs ----------------
__global__ __launch_bounds__(256) void proj_mfma_kernel(
    const float* __restrict__ keys, const float* __restrict__ queries,
    const float* __restrict__ values, const float* __restrict__ WQ,
    const float* __restrict__ WK, const float* __restrict__ WV,
    ushort_t* __restrict__ wsb) {
  int t = threadIdx.x;
  int z = blockIdx.z;
  int bh = blockIdx.y;
  int b = bh >> 3, h = bh & 7;
  int qbase = blockIdx.x * 64;
  const float* in; const float* W;
  if (z == 0)      { in = queries; W = WQ; }
  else if (z == 1) { in = keys;    W = WK; }
  else             { in = values;  W = WV; }
  const float* inbase = in + ((size_t)b * LL + qbase) * DM;
  const float* Wh = W + (size_t)h * DM * DH;

  __shared__ __align__(16) short As[64 * 40];
  __shared__ __align__(16) short Bs[64 * 40];

  int lane = t & 63, w = t >> 6;
  int quad = lane >> 4, l16 = lane & 15;

  f32x4 acc[4];
#pragma unroll
  for (int et = 0; et < 4; ++et) acc[et] = (f32x4){0.f, 0.f, 0.f, 0.f};

  for (int kt = 0; kt < 16; ++kt) {
    __syncthreads();
#pragma unroll
    for (int rep = 0; rep < 2; ++rep) {
      int f4 = t + rep * 256;
      int row = f4 >> 3, c4 = f4 & 7;
      float4 v = *(const float4*)(inbase + (size_t)row * DM + kt * 32 + c4 * 4);
      short* dst = &As[row * 40 + c4 * 4];
      dst[0] = (short)f2bf(v.x); dst[1] = (short)f2bf(v.y);
      dst[2] = (short)f2bf(v.z); dst[3] = (short)f2bf(v.w);
    }
#pragma unroll
    for (int rep = 0; rep < 2; ++rep) {
      int f4 = t + rep * 256;
      int d = f4 >> 4, e4 = f4 & 15;
      float4 v = *(const float4*)(Wh + (size_t)(kt * 32 + d) * 64 + e4 * 4);
      Bs[(e4 * 4 + 0) * 40 + d] = (short)f2bf(v.x);
      Bs[(e4 * 4 + 1) * 40 + d] = (short)f2bf(v.y);
      Bs[(e4 * 4 + 2) * 40 + d] = (short)f2bf(v.z);
      Bs[(e4 * 4 + 3) * 40 + d] = (short)f2bf(v.w);
    }
    __syncthreads();
    short8 a = *(const short8*)&As[(w * 16 + l16) * 40 + quad * 8];
#pragma unroll
    for (int et = 0; et < 4; ++et) {
      short8 bf = *(const short8*)&Bs[(et * 16 + l16) * 40 + quad * 8];
      acc[et] = __builtin_amdgcn_mfma_f32_16x16x32_bf16(a, bf, acc[et], 0, 0, 0);
    }
  }
  if (z < 2) {
    ushort_t* og = wsb + (z == 0 ? OFFB_Q : OFFB_K) + ((size_t)bh * LL + qbase) * 64;
#pragma unroll
    for (int et = 0; et < 4; ++et)
#pragma unroll
      for (int r = 0; r < 4; ++r)
        og[(size_t)(w * 16 + quad * 4 + r) * 64 + et * 16 + l16] = f2bf(acc[et][r]);
  } else {
    // V transposed: Vt[bh][e][l]
    ushort_t* og = wsb + OFFB_V + (size_t)bh * 64 * LL;
#pragma unroll
    for (int et = 0; et < 4; ++et)
#pragma unroll
      for (int r = 0; r < 4; ++r)
        og[(size_t)(et * 16 + l16) * LL + qbase + w * 16 + quad * 4 + r] = f2bf(acc[et][r]);
  }
}

// ---------------- Stats via MFMA: Sinv[bh,k] = 1/sum_q exp(SCALE * K[k,:]·Q[q,:]) ----------------
__global__ __launch_bounds__(256) void stats_kernel(const ushort_t* __restrict__ wsb,
                                                    float* __restrict__ Sinv) {
  const ushort_t* Qb = wsb + OFFB_Q;
  const ushort_t* Kb = wsb + OFFB_K;
  int t = threadIdx.x;
  int lane = t & 63, w = t >> 6;
  int quad = lane >> 4, l16 = lane & 15;
  int bh = blockIdx.y;
  int kbase = blockIdx.x * 64;

  __shared__ __align__(16) ushort_t Ksh[64 * 72];   // [k][d], stride 72 (144B, 16B-aligned)
  __shared__ __align__(16) ushort_t Qsh[64 * 72];   // [q][d]

  const ushort_t* Kg = Kb + ((size_t)bh * LL + kbase) * 64;
#pragma unroll
  for (int rep = 0; rep < 2; ++rep) {
    int f8 = t + rep * 256;
    int row = f8 >> 3, c8 = f8 & 7;
    *(short8*)&Ksh[row * 72 + c8 * 8] = *(const short8*)(Kg + (size_t)row * 64 + c8 * 8);
  }
  __syncthreads();
  // A-frag (K rows, wave-private) into registers once
  short8 ka0 = *(const short8*)&Ksh[(w * 16 + l16) * 72 + quad * 8];
  short8 ka1 = *(const short8*)&Ksh[(w * 16 + l16) * 72 + quad * 8 + 32];

  float rs[4] = {0.f, 0.f, 0.f, 0.f};
  const ushort_t* Qg = Qb + (size_t)bh * LL * 64;
  for (int qt = 0; qt < 32; ++qt) {
    __syncthreads();
#pragma unroll
    for (int rep = 0; rep < 2; ++rep) {
      int f8 = t + rep * 256;
      int row = f8 >> 3, c8 = f8 & 7;
      *(short8*)&Qsh[row * 72 + c8 * 8] = *(const short8*)(Qg + (size_t)(qt * 64 + row) * 64 + c8 * 8);
    }
    __syncthreads();
#pragma unroll
    for (int nt = 0; nt < 4; ++nt) {
      short8 b0 = *(const short8*)&Qsh[(nt * 16 + l16) * 72 + quad * 8];
      short8 b1 = *(const short8*)&Qsh[(nt * 16 + l16) * 72 + quad * 8 + 32];
      f32x4 y = (f32x4){0.f, 0.f, 0.f, 0.f};
      y = __builtin_amdgcn_mfma_f32_16x16x32_bf16(ka0, b0, y, 0, 0, 0);
      y = __builtin_amdgcn_mfma_f32_16x16x32_bf16(ka1, b1, y, 0, 0, 0);
#pragma unroll
      for (int r = 0; r < 4; ++r) rs[r] += __expf(y[r] * SCALE);
    }
  }
  // reduce over the 16 l16-lanes (cols = q) within each quad
#pragma unroll
  for (int r = 0; r < 4; ++r) {
    rs[r] += __shfl_xor(rs[r], 1);
    rs[r] += __shfl_xor(rs[r], 2);
    rs[r] += __shfl_xor(rs[r], 4);
    rs[r] += __shfl_xor(rs[r], 8);
  }
  if (l16 == 0) {
#pragma unroll
    for (int r = 0; r < 4; ++r)
      Sinv[(size_t)bh * LL + kbase + w * 16 + quad * 4 + r] = 1.0f / rs[r];
  }
}

// ---------------- Attention via MFMA: out = (exp(SCALE*QK^T)*Sinv) · V ----------------
__global__ __launch_bounds__(256) void attn_kernel(const ushort_t* __restrict__ wsb,
                                                   const float* __restrict__ Sinv,
                                                   float* __restrict__ out) {
  const ushort_t* Qb = wsb + OFFB_Q;
  const ushort_t* Kb = wsb + OFFB_K;
  const ushort_t* Vt = wsb + OFFB_V;
  int t = threadIdx.x;
  int lane = t & 63, w = t >> 6;
  int quad = lane >> 4, l16 = lane & 15;
  int bh = blockIdx.y;
  int b = bh >> 3, h = bh & 7;
  int qbase = blockIdx.x * 64;

  __shared__ __align__(16) ushort_t Ps[64 * 72];    // Q tile first, then P tiles
  __shared__ __align__(16) ushort_t Ksh[64 * 72];   // [k][d]
  __shared__ __align__(16) ushort_t Vsh[64 * 72];   // [e][k]  (from Vt)
  __shared__ float Ss[64];

  // stage Q tile into Ps
  const ushort_t* Qg = Qb + ((size_t)bh * LL + qbase) * 64;
#pragma unroll
  for (int rep = 0; rep < 2; ++rep) {
    int f8 = t + rep * 256;
    int row = f8 >> 3, c8 = f8 & 7;
    *(short8*)&Ps[row * 72 + c8 * 8] = *(const short8*)(Qg + (size_t)row * 64 + c8 * 8);
  }
  __syncthreads();
  short8 qa0 = *(const short8*)&Ps[(w * 16 + l16) * 72 + quad * 8];
  short8 qa1 = *(const short8*)&Ps[(w * 16 + l16) * 72 + quad * 8 + 32];

  f32x4 oacc[4];
#pragma unroll
  for (int nt = 0; nt < 4; ++nt) oacc[nt] = (f32x4){0.f, 0.f, 0.f, 0.f};

  const ushort_t* Kg = Kb + (size_t)bh * LL * 64;
  const ushort_t* Vg = Vt + (size_t)bh * 64 * LL;
  const float* Sg = Sinv + (size_t)bh * LL;

  for (int kt = 0; kt < 32; ++kt) {
    __syncthreads();   // prev iter done reading Ksh/Vsh (and Ps/qa on iter 0)
#pragma unroll
    for (int rep = 0; rep < 2; ++rep) {
      int f8 = t + rep * 256;
      int row = f8 >> 3, c8 = f8 & 7;
      *(short8*)&Ksh[row * 72 + c8 * 8] =
          *(const short8*)(Kg + (size_t)(kt * 64 + row) * 64 + c8 * 8);
      *(short8*)&Vsh[row * 72 + c8 * 8] =
          *(const short8*)(Vg + (size_t)row * LL + kt * 64 + c8 * 8);
    }
    if (t < 16) ((float4*)Ss)[t] = ((const float4*)(Sg + kt * 64))[t];
    __syncthreads();

    // QK^T -> P (wave-private rows: no barrier needed before PV)
#pragma unroll
    for (int nt = 0; nt < 4; ++nt) {
      short8 b0 = *(const short8*)&Ksh[(nt * 16 + l16) * 72 + quad * 8];
      short8 b1 = *(const short8*)&Ksh[(nt * 16 + l16) * 72 + quad * 8 + 32];
      f32x4 y = (f32x4){0.f, 0.f, 0.f, 0.f};
      y = __builtin_amdgcn_mfma_f32_16x16x32_bf16(qa0, b0, y, 0, 0, 0);
      y = __builtin_amdgcn_mfma_f32_16x16x32_bf16(qa1, b1, y, 0, 0, 0);
      float si = Ss[nt * 16 + l16];
#pragma unroll
      for (int r = 0; r < 4; ++r) {
        float p = __expf(y[r] * SCALE) * si;
        Ps[(w * 16 + quad * 4 + r) * 72 + nt * 16 + l16] = f2bf(p);
      }
    }

    // PV: A = P (own rows), B = V^T tile
    short8 pa0 = *(const short8*)&Ps[(w * 16 + l16) * 72 + quad * 8];
    short8 pa1 = *(const short8*)&Ps[(w * 16 + l16) * 72 + quad * 8 + 32];
#pragma unroll
    for (int nt = 0; nt < 4; ++nt) {
      short8 v0 = *(const short8*)&Vsh[(nt * 16 + l16) * 72 + quad * 8];
      short8 v1 = *(const short8*)&Vsh[(nt * 16 + l16) * 72 + quad * 8 + 32];
      oacc[nt] = __builtin_amdgcn_mfma_f32_16x16x32_bf16(pa0, v0, oacc[nt], 0, 0, 0);
      oacc[nt] = __builtin_amdgcn_mfma_f32_16x16x32_bf16(pa1, v1, oacc[nt], 0, 0, 0);
    }
  }

  float* og = out + ((size_t)b * LL + qbase) * (HH * DH) + h * DH;
#pragma unroll
  for (int nt = 0; nt < 4; ++nt)
#pragma unroll
    for (int r = 0; r < 4; ++r)
      og[(size_t)(w * 16 + quad * 4 + r) * (HH * DH) + nt * 16 + l16] = oacc[nt][r];
}

extern "C" void kernel_launch(void* const* d_in, const int* in_sizes, int n_in,
                              void* d_out, int out_size, void* d_ws, size_t ws_size,
                              hipStream_t stream) {
  const float* keys    = (const float*)d_in[0];
  const float* queries = (const float*)d_in[1];
  const float* values  = (const float*)d_in[2];
  const float* WQ      = (const float*)d_in[3];
  const float* WK      = (const float*)d_in[4];
  const float* WV      = (const float*)d_in[5];
  float* out = (float*)d_out;
  ushort_t* wsb = (ushort_t*)d_ws;
  float* Sinv = (float*)(wsb + OFFB_S);

  proj_mfma_kernel<<<dim3(LL / 64, BH, 3), 256, 0, stream>>>(keys, queries, values, WQ, WK, WV, wsb);
  stats_kernel<<<dim3(LL / 64, BH), 256, 0, stream>>>(wsb, Sinv);
  attn_kernel<<<dim3(LL / 64, BH), 256, 0, stream>>>(wsb, Sinv, out);
}